// Round 12
// baseline (385.389 us; speedup 1.0000x reference)
//
#include <hip/hip_runtime.h>

// EdgeBlock: out = relu(concat(xn[src], xn[dst], xe) @ W1 + b1) @ W2 + b2
// R12: algebraic split. Precompute Ps=Xn@W1s, Pd=Xn@W1d per NODE (50k rows,
// bf16, col-swizzled to match MFMA C-fragment layout). Main kernel per edge:
// H = relu(Xe@W1e + Ps[src] + Pd[dst] + b1); out = H@W2 + b2 -> 8 K-steps
// instead of 16, gather moved from GEMM loop to an 8B-per-lane epilogue add.
// All staging/swizzle/epilogue paths reused from R11 (HW-verified).

typedef __attribute__((ext_vector_type(8))) short short8;
typedef __attribute__((ext_vector_type(4))) float f32x4;
typedef __attribute__((address_space(1))) unsigned int* gp1_t;
typedef __attribute__((address_space(3))) unsigned int* lp3_t;

#define LDO 260

__device__ __forceinline__ unsigned short f2b(float f) {
  unsigned int u = __float_as_uint(f);
  return (unsigned short)((u + 0x7FFFu + ((u >> 16) & 1u)) >> 16);
}
__device__ __forceinline__ unsigned int f2b2(float lo, float hi) {
  return (unsigned int)f2b(lo) | ((unsigned int)f2b(hi) << 16);
}
__device__ __forceinline__ float b2f(unsigned int u) {
  return __uint_as_float((u & 0xffffu) << 16);
}
__device__ __forceinline__ void gload16(const void* g, void* l) {
  __builtin_amdgcn_global_load_lds((gp1_t)g, (lp3_t)l, 16, 0, 0);
}

// Pack W[k][256] -> steps of [256 n][8 s][8 j] bf16 (32KB/step).
// Slot s of row n holds source k-group (s ^ (n&7)). (R8/R11-verified.)
__global__ void prep_w_kernel(const float* __restrict__ w,
                              unsigned short* __restrict__ wp, int total) {
  int i = blockIdx.x * 256 + threadIdx.x;
  if (i >= total) return;
  int step = i >> 14;
  int rem = i & 16383;
  int n = rem >> 6;
  int s = (rem >> 3) & 7;
  int j = i & 7;
  int k = step * 64 + (((s ^ (n & 7)) << 3) | j);
  wp[i] = f2b(w[(size_t)k * 256 + n]);
}

// ---- Node precompute: P[node] = xnode @ W1seg (no bias), bf16, col-swizzled
// P elem index p = (col&15)*16 + (col>>4). Block: 256 node rows x 256 cols,
// K=256 (4 steps of 64). blockIdx.y selects segment (0=src table, 1=dst).
__global__ __launch_bounds__(512) void node_p_kernel(
    const float* __restrict__ xnode, const unsigned short* __restrict__ wtab,
    unsigned short* __restrict__ Pbase, int NN) {
  __shared__ __align__(16) char smem[65536];   // A dbuf 2x32KB

  const int t = threadIdx.x, w = t >> 6, l = t & 63;
  const int lr = l & 15, lk = l >> 4;
  const int wr = w >> 2, wc = w & 3;
  const int nbase = blockIdx.x * 256;
  const char* wt = (const char*)wtab + blockIdx.y * 131072;
  unsigned short* P = Pbase + (size_t)blockIdx.y * NN * 256;

  const int r2 = t >> 1;
  int row2 = nbase + r2;
  if (row2 >= NN) row2 = NN - 1;

  f32x4 acc[8][4];
#pragma unroll
  for (int i = 0; i < 8; ++i)
#pragma unroll
    for (int j = 0; j < 4; ++j) acc[i][j] = (f32x4)0.0f;

  auto stageA = [&](int s, int buf) {     // xnode f32 -> bf16, j^rb swizzle
    const int rb = r2 & 7;
    float4 v[8];
#pragma unroll
    for (int jj = 0; jj < 4; ++jj) {
      const int j = (t & 1) * 4 + jj;
      const float* p = xnode + (size_t)row2 * 256 + s * 64 + j * 8;
      v[2 * jj] = ((const float4*)p)[0];
      v[2 * jj + 1] = ((const float4*)p)[1];
    }
#pragma unroll
    for (int jj = 0; jj < 4; ++jj) {
      const int j = (t & 1) * 4 + jj;
      uint4 u;
      u.x = f2b2(v[2 * jj].x, v[2 * jj].y);
      u.y = f2b2(v[2 * jj].z, v[2 * jj].w);
      u.z = f2b2(v[2 * jj + 1].x, v[2 * jj + 1].y);
      u.w = f2b2(v[2 * jj + 1].z, v[2 * jj + 1].w);
      *(uint4*)(smem + buf * 32768 + r2 * 128 + ((j ^ rb) << 4)) = u;
    }
  };

  stageA(0, 0);
  __syncthreads();
  for (int k = 0; k < 4; ++k) {
    if (k + 1 < 4) stageA(k + 1, (k + 1) & 1);
    const char* A = smem + (k & 1) * 32768;
    const char* wb = wt + k * 32768;
    __builtin_amdgcn_s_setprio(1);
#pragma unroll
    for (int ks = 0; ks < 2; ++ks) {
      short8 bf[4];
#pragma unroll
      for (int ni = 0; ni < 4; ++ni) {
        const int n = wc * 64 + ni * 16 + lr;
        bf[ni] = *(const short8*)(wb + n * 128 + (((ks * 4 + lk) ^ (n & 7)) << 4));
      }
#pragma unroll
      for (int mi = 0; mi < 8; ++mi) {
        const int m = wr * 128 + mi * 16 + lr;
        short8 af = *(const short8*)(A + m * 128 + (((ks * 4 + lk) ^ (m & 7)) << 4));
#pragma unroll
        for (int ni = 0; ni < 4; ++ni)
          acc[mi][ni] = __builtin_amdgcn_mfma_f32_16x16x32_bf16(
              af, bf[ni], acc[mi][ni], 0, 0, 0);
      }
    }
    __builtin_amdgcn_s_setprio(0);
    __syncthreads();
  }

  // store P bf16 col-swizzled: per (mi,r) one 8B store covering ni=0..3
#pragma unroll
  for (int mi = 0; mi < 8; ++mi)
#pragma unroll
    for (int r = 0; r < 4; ++r) {
      const int node = nbase + wr * 128 + mi * 16 + lk * 4 + r;
      if (node < NN) {
        uint2 o;
        o.x = f2b2(acc[mi][0][r], acc[mi][1][r]);
        o.y = f2b2(acc[mi][2][r], acc[mi][3][r]);
        *(uint2*)((char*)P + (size_t)node * 512 + lr * 32 + wc * 8) = o;
      }
    }
}

// ---- Main edge kernel: H = relu(Xe@W1e + Ps[src] + Pd[dst] + b1); out = H@W2+b2
__global__ __launch_bounds__(512) void edge_mlp_p(
    const float* __restrict__ xedge, const int* __restrict__ eidx,
    const unsigned short* __restrict__ Ps, const unsigned short* __restrict__ Pd,
    const unsigned short* __restrict__ wt1ep, const float* __restrict__ b1,
    const unsigned short* __restrict__ wt2p, const float* __restrict__ b2,
    float* __restrict__ out, int E) {
  __shared__ __align__(16) char smem[133120];  // A 2x32K @0, B 2x32K @64K, idx 2K @128K

  const int t = threadIdx.x, w = t >> 6, l = t & 63;
  const int lr = l & 15, lk = l >> 4;
  const int wr = w >> 2, wc = w & 3;
  const int ebase = blockIdx.x * 256;

  int* sIdx = (int*)(smem + 131072);
  int* dIdx = (int*)(smem + 131072 + 1024);
  {
    const int i = t & 255;
    int e = ebase + i;
    if (e >= E) e = E - 1;
    if (t < 256) sIdx[i] = eidx[e];
    else         dIdx[i] = eidx[(size_t)E + e];
  }

  const int r2 = t >> 1;
  int e2 = ebase + r2;
  if (e2 >= E) e2 = E - 1;

  f32x4 acc[8][4];
#pragma unroll
  for (int i = 0; i < 8; ++i)
#pragma unroll
    for (int j = 0; j < 4; ++j) acc[i][j] = (f32x4)0.0f;

  auto stageB = [&](int step, int buf) {   // 32KB packed W1e step, linear
    const char* g = (const char*)wt1ep + (size_t)step * 32768 + (t << 4);
    char* d = smem + 65536 + buf * 32768 + (w << 10) + (l << 4);
#pragma unroll
    for (int q = 0; q < 4; ++q) gload16(g + q * 8192, d + q * 8192);
  };
  auto stageA = [&](int s, int buf) {      // xedge f32 -> bf16, j^rb swizzle
    const int rb = r2 & 7;
    float4 v[8];
#pragma unroll
    for (int jj = 0; jj < 4; ++jj) {
      const int j = (t & 1) * 4 + jj;
      const float* p = xedge + (size_t)e2 * 256 + s * 64 + j * 8;
      v[2 * jj] = ((const float4*)p)[0];
      v[2 * jj + 1] = ((const float4*)p)[1];
    }
#pragma unroll
    for (int jj = 0; jj < 4; ++jj) {
      const int j = (t & 1) * 4 + jj;
      uint4 u;
      u.x = f2b2(v[2 * jj].x, v[2 * jj].y);
      u.y = f2b2(v[2 * jj].z, v[2 * jj].w);
      u.z = f2b2(v[2 * jj + 1].x, v[2 * jj + 1].y);
      u.w = f2b2(v[2 * jj + 1].z, v[2 * jj + 1].w);
      *(uint4*)(smem + buf * 32768 + r2 * 128 + ((j ^ rb) << 4)) = u;
    }
  };
  auto compute = [&](int k) {
    const char* A = smem + (k & 1) * 32768;
    const char* B = smem + 65536 + (k & 1) * 32768;
    __builtin_amdgcn_s_setprio(1);
#pragma unroll
    for (int ks = 0; ks < 2; ++ks) {
      short8 bf[4];
#pragma unroll
      for (int ni = 0; ni < 4; ++ni) {
        const int n = wc * 64 + ni * 16 + lr;
        bf[ni] = *(const short8*)(B + n * 128 + (((ks * 4 + lk) ^ (n & 7)) << 4));
      }
#pragma unroll
      for (int mi = 0; mi < 8; ++mi) {
        const int m = wr * 128 + mi * 16 + lr;
        short8 af = *(const short8*)(A + m * 128 + (((ks * 4 + lk) ^ (m & 7)) << 4));
#pragma unroll
        for (int ni = 0; ni < 4; ++ni)
          acc[mi][ni] = __builtin_amdgcn_mfma_f32_16x16x32_bf16(
              af, bf[ni], acc[mi][ni], 0, 0, 0);
      }
    }
    __builtin_amdgcn_s_setprio(0);
  };

  // ---- GEMM1: Xe@W1e, 4 K-steps of 64, A/B dbuf ----
  stageA(0, 0);
  stageB(0, 0);
  __syncthreads();
  for (int k = 0; k < 4; ++k) {
    if (k + 1 < 4) {
      stageB(k + 1, (k + 1) & 1);
      stageA(k + 1, (k + 1) & 1);
    }
    compute(k);
    __syncthreads();
  }

  // ---- P-gather add + bias + ReLU -> Hs (Hs aliases A/B bufs) ----
  char* Hs = smem;
  float bias4[4];
#pragma unroll
  for (int ni = 0; ni < 4; ++ni) bias4[ni] = b1[wc * 64 + ni * 16 + lr];
#pragma unroll
  for (int mi = 0; mi < 8; ++mi) {
    uint2 pls[4], pld[4];
#pragma unroll
    for (int r = 0; r < 4; ++r) {
      const int m = wr * 128 + mi * 16 + lk * 4 + r;
      const int si = sIdx[m], di = dIdx[m];
      pls[r] = *(const uint2*)((const char*)Ps + (size_t)si * 512 + lr * 32 + wc * 8);
      pld[r] = *(const uint2*)((const char*)Pd + (size_t)di * 512 + lr * 32 + wc * 8);
    }
#pragma unroll
    for (int ni = 0; ni < 4; ++ni) {
      const int col = wc * 64 + ni * 16 + lr;
      const int cole = col & ~1;
      const int chunk = cole >> 3;
      const int cb = (cole & 6) * 2;
      float v[4], p[4];
#pragma unroll
      for (int r = 0; r < 4; ++r) {
        const unsigned us = (ni < 2) ? (pls[r].x >> (16 * ni)) : (pls[r].y >> (16 * (ni - 2)));
        const unsigned ud = (ni < 2) ? (pld[r].x >> (16 * ni)) : (pld[r].y >> (16 * (ni - 2)));
        float x = acc[mi][ni][r] + bias4[ni] + b2f(us) + b2f(ud);
        v[r] = x > 0.f ? x : 0.f;
        acc[mi][ni][r] = 0.f;
      }
#pragma unroll
      for (int r = 0; r < 4; ++r) p[r] = __shfl_xor(v[r], 1, 64);
      const int r0 = (lr & 1) ? 2 : 0;
#pragma unroll
      for (int rr = 0; rr < 2; ++rr) {
        const int r = r0 + rr;
        const int row = wr * 128 + mi * 16 + lk * 4 + r;
        const float lo = (lr & 1) ? p[r] : v[r];
        const float hi = (lr & 1) ? v[r] : p[r];
        *(unsigned int*)(Hs + row * 512 + ((chunk ^ (row & 7)) << 4) + cb) =
            f2b2(lo, hi);
      }
    }
  }
  __syncthreads();

  // ---- GEMM2: 4 K-steps; A from Hs, B direct global ping-pong ----
  short8 bfA[4], bfB[4];
  auto loadB2 = [&](int pair, short8 (&bf)[4]) {
    const char* wb = (const char*)wt2p + (pair >> 1) * 32768;
    const int ksl = (pair & 1) * 4 + lk;
#pragma unroll
    for (int ni = 0; ni < 4; ++ni) {
      const int n = wc * 64 + ni * 16 + lr;
      bf[ni] = *(const short8*)(wb + n * 128 + ((ksl ^ (n & 7)) << 4));
    }
  };
  auto mfmaH = [&](int pair, short8 (&bf)[4]) {
    const int j = (pair >> 1) * 8 + (pair & 1) * 4 + lk;
    __builtin_amdgcn_s_setprio(1);
#pragma unroll
    for (int mi = 0; mi < 8; ++mi) {
      const int m = wr * 128 + mi * 16 + lr;
      short8 af = *(const short8*)(Hs + m * 512 + ((j ^ (m & 7)) << 4));
#pragma unroll
      for (int ni = 0; ni < 4; ++ni)
        acc[mi][ni] = __builtin_amdgcn_mfma_f32_16x16x32_bf16(
            af, bf[ni], acc[mi][ni], 0, 0, 0);
    }
    __builtin_amdgcn_s_setprio(0);
  };
  loadB2(0, bfA);
#pragma unroll
  for (int pair = 0; pair < 8; pair += 2) {
    if (pair + 1 < 8) loadB2(pair + 1, bfB);
    mfmaH(pair, bfA);
    if (pair + 2 < 8) loadB2(pair + 2, bfA);
    if (pair + 1 < 8) mfmaH(pair + 1, bfB);
  }

  // ---- bias + coalesced f32 store via LDS (four 64-row passes) ----
  float* outst = (float*)smem;
#pragma unroll
  for (int p = 0; p < 4; ++p) {
    __syncthreads();
    if (wr == (p >> 1)) {
#pragma unroll
      for (int ni = 0; ni < 4; ++ni) {
        const int col = wc * 64 + ni * 16 + lr;
        const float bias = b2[col];
#pragma unroll
        for (int mh = 0; mh < 4; ++mh) {
          const int mi = (p & 1) * 4 + mh;
#pragma unroll
          for (int r = 0; r < 4; ++r)
            outst[(mh * 16 + lk * 4 + r) * LDO + col] = acc[mi][ni][r] + bias;
        }
      }
    }
    __syncthreads();
#pragma unroll
    for (int it = 0; it < 8; ++it) {
      const int idx = it * 2048 + t * 4;
      const int lrow = idx >> 8;
      const int cc = idx & 255;
      const int grow = ebase + p * 64 + lrow;
      if (grow < E)
        *(float4*)(out + (size_t)grow * 256 + cc) =
            *(const float4*)(outst + lrow * LDO + cc);
    }
  }
}

// ---- Fallback (small ws): R11 full kernel, f32 staging only (512KB tables) ----
__global__ __launch_bounds__(512) void edge_mlp_fb(
    const float* __restrict__ xnode, const float* __restrict__ xedge,
    const int* __restrict__ eidx,
    const unsigned short* __restrict__ wt1p, const float* __restrict__ b1,
    const unsigned short* __restrict__ wt2p, const float* __restrict__ b2,
    float* __restrict__ out, int E) {
  __shared__ __align__(16) char smem[131072];

  const int t = threadIdx.x, w = t >> 6, l = t & 63;
  const int lr = l & 15, lk = l >> 4;
  const int wr = w >> 2, wc = w & 3;
  const int ebase = blockIdx.x * 256;

  const int r2 = t >> 1;
  int e2 = ebase + r2;
  if (e2 >= E) e2 = E - 1;
  const int ns2 = eidx[e2], nd2 = eidx[(size_t)E + e2];

  f32x4 acc[8][4];
#pragma unroll
  for (int i = 0; i < 8; ++i)
#pragma unroll
    for (int j = 0; j < 4; ++j) acc[i][j] = (f32x4)0.0f;

  auto stageB = [&](int step, int buf) {
    const char* g = (const char*)wt1p + (size_t)step * 32768 + (t << 4);
    char* d = smem + 65536 + buf * 32768 + (w << 10) + (l << 4);
#pragma unroll
    for (int q = 0; q < 4; ++q) gload16(g + q * 8192, d + q * 8192);
  };
  auto stageA_f32 = [&](const float* base, int rowid, int coloff, int buf) {
    const int rb = r2 & 7;
    float4 v[8];
#pragma unroll
    for (int jj = 0; jj < 4; ++jj) {
      const int j = (t & 1) * 4 + jj;
      const float* p = base + (size_t)rowid * 256 + coloff + j * 8;
      v[2 * jj] = ((const float4*)p)[0];
      v[2 * jj + 1] = ((const float4*)p)[1];
    }
#pragma unroll
    for (int jj = 0; jj < 4; ++jj) {
      const int j = (t & 1) * 4 + jj;
      uint4 u;
      u.x = f2b2(v[2 * jj].x, v[2 * jj].y);
      u.y = f2b2(v[2 * jj].z, v[2 * jj].w);
      u.z = f2b2(v[2 * jj + 1].x, v[2 * jj + 1].y);
      u.w = f2b2(v[2 * jj + 1].z, v[2 * jj + 1].w);
      *(uint4*)(smem + buf * 32768 + r2 * 128 + ((j ^ rb) << 4)) = u;
    }
  };
  auto stageA = [&](int s, int buf) {
    if (s < 4)       stageA_f32(xnode, ns2, s * 64, buf);
    else if (s < 8)  stageA_f32(xnode, nd2, (s - 4) * 64, buf);
    else             stageA_f32(xedge, e2, (s - 8) * 64, buf);
  };
  auto compute = [&](int k) {
    const char* A = smem + (k & 1) * 32768;
    const char* B = smem + 65536 + (k & 1) * 32768;
    __builtin_amdgcn_s_setprio(1);
#pragma unroll
    for (int ks = 0; ks < 2; ++ks) {
      short8 bf[4];
#pragma unroll
      for (int ni = 0; ni < 4; ++ni) {
        const int n = wc * 64 + ni * 16 + lr;
        bf[ni] = *(const short8*)(B + n * 128 + (((ks * 4 + lk) ^ (n & 7)) << 4));
      }
#pragma unroll
      for (int mi = 0; mi < 8; ++mi) {
        const int m = wr * 128 + mi * 16 + lr;
        short8 af = *(const short8*)(A + m * 128 + (((ks * 4 + lk) ^ (m & 7)) << 4));
#pragma unroll
        for (int ni = 0; ni < 4; ++ni)
          acc[mi][ni] = __builtin_amdgcn_mfma_f32_16x16x32_bf16(
              af, bf[ni], acc[mi][ni], 0, 0, 0);
      }
    }
    __builtin_amdgcn_s_setprio(0);
  };

  stageA(0, 0);
  stageB(0, 0);
  __syncthreads();
  for (int k = 0; k < 12; ++k) {
    if (k + 1 < 12) {
      stageB(k + 1, (k + 1) & 1);
      stageA(k + 1, (k + 1) & 1);
    }
    compute(k);
    __syncthreads();
  }

  char* Hs = smem;
#pragma unroll
  for (int ni = 0; ni < 4; ++ni) {
    const int col = wc * 64 + ni * 16 + lr;
    const float bias = b1[col];
    const int cole = col & ~1;
    const int chunk = cole >> 3;
    const int cb = (cole & 6) * 2;
#pragma unroll
    for (int mi = 0; mi < 8; ++mi) {
      float v[4], p[4];
#pragma unroll
      for (int r = 0; r < 4; ++r) {
        float x = acc[mi][ni][r] + bias;
        v[r] = x > 0.f ? x : 0.f;
        acc[mi][ni][r] = 0.f;
      }
#pragma unroll
      for (int r = 0; r < 4; ++r) p[r] = __shfl_xor(v[r], 1, 64);
      const int r0 = (lr & 1) ? 2 : 0;
#pragma unroll
      for (int rr = 0; rr < 2; ++rr) {
        const int r = r0 + rr;
        const int row = wr * 128 + mi * 16 + lk * 4 + r;
        const float lo = (lr & 1) ? p[r] : v[r];
        const float hi = (lr & 1) ? v[r] : p[r];
        *(unsigned int*)(Hs + row * 512 + ((chunk ^ (row & 7)) << 4) + cb) =
            f2b2(lo, hi);
      }
    }
  }
  __syncthreads();

  short8 bfA[4], bfB[4];
  auto loadB2 = [&](int pair, short8 (&bf)[4]) {
    const char* wb = (const char*)wt2p + (pair >> 1) * 32768;
    const int ksl = (pair & 1) * 4 + lk;
#pragma unroll
    for (int ni = 0; ni < 4; ++ni) {
      const int n = wc * 64 + ni * 16 + lr;
      bf[ni] = *(const short8*)(wb + n * 128 + ((ksl ^ (n & 7)) << 4));
    }
  };
  auto mfmaH = [&](int pair, short8 (&bf)[4]) {
    const int j = (pair >> 1) * 8 + (pair & 1) * 4 + lk;
    __builtin_amdgcn_s_setprio(1);
#pragma unroll
    for (int mi = 0; mi < 8; ++mi) {
      const int m = wr * 128 + mi * 16 + lr;
      short8 af = *(const short8*)(Hs + m * 512 + ((j ^ (m & 7)) << 4));
#pragma unroll
      for (int ni = 0; ni < 4; ++ni)
        acc[mi][ni] = __builtin_amdgcn_mfma_f32_16x16x32_bf16(
            af, bf[ni], acc[mi][ni], 0, 0, 0);
    }
    __builtin_amdgcn_s_setprio(0);
  };
  loadB2(0, bfA);
#pragma unroll
  for (int pair = 0; pair < 8; pair += 2) {
    if (pair + 1 < 8) loadB2(pair + 1, bfB);
    mfmaH(pair, bfA);
    if (pair + 2 < 8) loadB2(pair + 2, bfA);
    if (pair + 1 < 8) mfmaH(pair + 1, bfB);
  }

  float* outst = (float*)smem;
#pragma unroll
  for (int p = 0; p < 4; ++p) {
    __syncthreads();
    if (wr == (p >> 1)) {
#pragma unroll
      for (int ni = 0; ni < 4; ++ni) {
        const int col = wc * 64 + ni * 16 + lr;
        const float bias = b2[col];
#pragma unroll
        for (int mh = 0; mh < 4; ++mh) {
          const int mi = (p & 1) * 4 + mh;
#pragma unroll
          for (int r = 0; r < 4; ++r)
            outst[(mh * 16 + lk * 4 + r) * LDO + col] = acc[mi][ni][r] + bias;
        }
      }
    }
    __syncthreads();
#pragma unroll
    for (int it = 0; it < 8; ++it) {
      const int idx = it * 2048 + t * 4;
      const int lrow = idx >> 8;
      const int cc = idx & 255;
      const int grow = ebase + p * 64 + lrow;
      if (grow < E)
        *(float4*)(out + (size_t)grow * 256 + cc) =
            *(const float4*)(outst + lrow * LDO + cc);
    }
  }
}

extern "C" void kernel_launch(void* const* d_in, const int* in_sizes, int n_in,
                              void* d_out, int out_size, void* d_ws, size_t ws_size,
                              hipStream_t stream) {
  const float* xnode = (const float*)d_in[0];
  const float* xedge = (const float*)d_in[1];
  const int* eidx = (const int*)d_in[2];
  const float* W1 = (const float*)d_in[3];
  const float* b1 = (const float*)d_in[4];
  const float* W2 = (const float*)d_in[5];
  const float* b2 = (const float*)d_in[6];
  float* out = (float*)d_out;

  const int NN = in_sizes[0] / 256;   // 50000
  const int E = in_sizes[1] / 256;    // 300000
  const int grid = (E + 255) / 256;

  char* ws = (char*)d_ws;
  const size_t need_new = 4 * 131072 + (size_t)2 * NN * 512;

  if (ws_size >= need_new) {
    unsigned short* wt1sp = (unsigned short*)ws;                    // 128KB
    unsigned short* wt1dp = (unsigned short*)(ws + 131072);         // 128KB
    unsigned short* wt1ep = (unsigned short*)(ws + 262144);         // 128KB
    unsigned short* wt2p  = (unsigned short*)(ws + 393216);         // 128KB
    unsigned short* Ps    = (unsigned short*)(ws + 524288);         // NN*512B x2
    unsigned short* Pd    = Ps + (size_t)NN * 256;

    prep_w_kernel<<<256, 256, 0, stream>>>(W1, wt1sp, 65536);
    prep_w_kernel<<<256, 256, 0, stream>>>(W1 + 65536, wt1dp, 65536);
    prep_w_kernel<<<256, 256, 0, stream>>>(W1 + 131072, wt1ep, 65536);
    prep_w_kernel<<<256, 256, 0, stream>>>(W2, wt2p, 65536);

    node_p_kernel<<<dim3((NN + 255) / 256, 2), 512, 0, stream>>>(xnode, wt1sp,
                                                                 Ps, NN);
    edge_mlp_p<<<grid, 512, 0, stream>>>(xedge, eidx, Ps, Pd, wt1ep, b1,
                                         wt2p, b2, out, E);
  } else {
    unsigned short* wt1p = (unsigned short*)ws;                     // 12x32KB
    unsigned short* wt2p = (unsigned short*)(ws + 12 * 32768);      //  4x32KB
    prep_w_kernel<<<(12 * 16384 + 255) / 256, 256, 0, stream>>>(W1, wt1p,
                                                                12 * 16384);
    prep_w_kernel<<<256, 256, 0, stream>>>(W2, wt2p, 65536);
    edge_mlp_fb<<<grid, 512, 0, stream>>>(xnode, xedge, eidx, wt1p, b1,
                                          wt2p, b2, out, E);
  }
}

// Round 13
// 379.978 us; speedup vs baseline: 1.0142x; 1.0142x over previous
//
#include <hip/hip_runtime.h>

// EdgeBlock: out = relu(concat(xn[src], xn[dst], xe) @ W1 + b1) @ W2 + b2
// R13: R12 algebra (P-split) + max block concurrency. Edge kernel: BM=64,
// 256thr/4waves, LDS 32.5KB -> 4 blocks/CU (16 waves). B direct-to-VGPR for
// both GEMMs. A-dbuf 16KB; Hs 32KB aliases it; outst aliases Hs. All
// swizzle/epilogue schemes verbatim from R11/R12 (HW-verified).

typedef __attribute__((ext_vector_type(8))) short short8;
typedef __attribute__((ext_vector_type(4))) float f32x4;
typedef __attribute__((address_space(1))) unsigned int* gp1_t;
typedef __attribute__((address_space(3))) unsigned int* lp3_t;

#define LDO 260

__device__ __forceinline__ unsigned short f2b(float f) {
  unsigned int u = __float_as_uint(f);
  return (unsigned short)((u + 0x7FFFu + ((u >> 16) & 1u)) >> 16);
}
__device__ __forceinline__ unsigned int f2b2(float lo, float hi) {
  return (unsigned int)f2b(lo) | ((unsigned int)f2b(hi) << 16);
}
__device__ __forceinline__ float b2f(unsigned int u) {
  return __uint_as_float((u & 0xffffu) << 16);
}
__device__ __forceinline__ void gload16(const void* g, void* l) {
  __builtin_amdgcn_global_load_lds((gp1_t)g, (lp3_t)l, 16, 0, 0);
}

// Pack W[k][256] -> steps of [256 n][8 s][8 j] bf16 (32KB/step).
// Slot s of row n holds source k-group (s ^ (n&7)). (R8/R11-verified.)
__global__ void prep_w_kernel(const float* __restrict__ w,
                              unsigned short* __restrict__ wp, int total) {
  int i = blockIdx.x * 256 + threadIdx.x;
  if (i >= total) return;
  int step = i >> 14;
  int rem = i & 16383;
  int n = rem >> 6;
  int s = (rem >> 3) & 7;
  int j = i & 7;
  int k = step * 64 + (((s ^ (n & 7)) << 3) | j);
  wp[i] = f2b(w[(size_t)k * 256 + n]);
}

// ---- Node precompute (R12-verified, unchanged): P = xnode @ W1seg, bf16,
// col-swizzled p=(col&15)*16+(col>>4) stored as lr*32 + wc*8 byte offsets.
__global__ __launch_bounds__(512) void node_p_kernel(
    const float* __restrict__ xnode, const unsigned short* __restrict__ wtab,
    unsigned short* __restrict__ Pbase, int NN) {
  __shared__ __align__(16) char smem[65536];

  const int t = threadIdx.x, w = t >> 6, l = t & 63;
  const int lr = l & 15, lk = l >> 4;
  const int wr = w >> 2, wc = w & 3;
  const int nbase = blockIdx.x * 256;
  const char* wt = (const char*)wtab + blockIdx.y * 131072;
  unsigned short* P = Pbase + (size_t)blockIdx.y * NN * 256;

  const int r2 = t >> 1;
  int row2 = nbase + r2;
  if (row2 >= NN) row2 = NN - 1;

  f32x4 acc[8][4];
#pragma unroll
  for (int i = 0; i < 8; ++i)
#pragma unroll
    for (int j = 0; j < 4; ++j) acc[i][j] = (f32x4)0.0f;

  auto stageA = [&](int s, int buf) {
    const int rb = r2 & 7;
    float4 v[8];
#pragma unroll
    for (int jj = 0; jj < 4; ++jj) {
      const int j = (t & 1) * 4 + jj;
      const float* p = xnode + (size_t)row2 * 256 + s * 64 + j * 8;
      v[2 * jj] = ((const float4*)p)[0];
      v[2 * jj + 1] = ((const float4*)p)[1];
    }
#pragma unroll
    for (int jj = 0; jj < 4; ++jj) {
      const int j = (t & 1) * 4 + jj;
      uint4 u;
      u.x = f2b2(v[2 * jj].x, v[2 * jj].y);
      u.y = f2b2(v[2 * jj].z, v[2 * jj].w);
      u.z = f2b2(v[2 * jj + 1].x, v[2 * jj + 1].y);
      u.w = f2b2(v[2 * jj + 1].z, v[2 * jj + 1].w);
      *(uint4*)(smem + buf * 32768 + r2 * 128 + ((j ^ rb) << 4)) = u;
    }
  };

  stageA(0, 0);
  __syncthreads();
  for (int k = 0; k < 4; ++k) {
    if (k + 1 < 4) stageA(k + 1, (k + 1) & 1);
    const char* A = smem + (k & 1) * 32768;
    const char* wb = wt + k * 32768;
    __builtin_amdgcn_s_setprio(1);
#pragma unroll
    for (int ks = 0; ks < 2; ++ks) {
      short8 bf[4];
#pragma unroll
      for (int ni = 0; ni < 4; ++ni) {
        const int n = wc * 64 + ni * 16 + lr;
        bf[ni] = *(const short8*)(wb + n * 128 + (((ks * 4 + lk) ^ (n & 7)) << 4));
      }
#pragma unroll
      for (int mi = 0; mi < 8; ++mi) {
        const int m = wr * 128 + mi * 16 + lr;
        short8 af = *(const short8*)(A + m * 128 + (((ks * 4 + lk) ^ (m & 7)) << 4));
#pragma unroll
        for (int ni = 0; ni < 4; ++ni)
          acc[mi][ni] = __builtin_amdgcn_mfma_f32_16x16x32_bf16(
              af, bf[ni], acc[mi][ni], 0, 0, 0);
      }
    }
    __builtin_amdgcn_s_setprio(0);
    __syncthreads();
  }

#pragma unroll
  for (int mi = 0; mi < 8; ++mi)
#pragma unroll
    for (int r = 0; r < 4; ++r) {
      const int node = nbase + wr * 128 + mi * 16 + lk * 4 + r;
      if (node < NN) {
        uint2 o;
        o.x = f2b2(acc[mi][0][r], acc[mi][1][r]);
        o.y = f2b2(acc[mi][2][r], acc[mi][3][r]);
        *(uint2*)((char*)P + (size_t)node * 512 + lr * 32 + wc * 8) = o;
      }
    }
}

// ---- Main edge kernel (light blocks): H = relu(Xe@W1e + Ps[s] + Pd[d] + b1);
// out = H@W2 + b2. BM=64, 4 waves (1Mx4N), 4 blocks/CU.
__global__ __launch_bounds__(256, 4) void edge_mlp_lite(
    const float* __restrict__ xedge, const int* __restrict__ eidx,
    const unsigned short* __restrict__ Ps, const unsigned short* __restrict__ Pd,
    const unsigned short* __restrict__ wt1ep, const float* __restrict__ b1,
    const unsigned short* __restrict__ wt2p, const float* __restrict__ b2,
    float* __restrict__ out, int E) {
  __shared__ __align__(16) char smem[33280];  // 32KB union + 512B idx

  const int t = threadIdx.x, w = t >> 6, l = t & 63;
  const int lr = l & 15, lk = l >> 4;
  const int ebase = blockIdx.x * 64;

  int* sIdx = (int*)(smem + 32768);
  int* dIdx = (int*)(smem + 33024);
  if (t < 128) {
    const int i = t & 63;
    int e = ebase + i;
    if (e >= E) e = E - 1;
    if (t < 64) sIdx[i] = eidx[e];
    else        dIdx[i] = eidx[(size_t)E + e];
  }

  const int r4 = t >> 2, q = t & 3;
  int e4 = ebase + r4;
  if (e4 >= E) e4 = E - 1;

  f32x4 acc[4][4];
#pragma unroll
  for (int i = 0; i < 4; ++i)
#pragma unroll
    for (int j = 0; j < 4; ++j) acc[i][j] = (f32x4)0.0f;

  // stage 64x64 bf16 A-tile (xedge f32 -> bf16), slot j^(row&7) swizzle
  auto stageA = [&](int s, int buf) {
    const int rb = r4 & 7;
    float4 v[4];
#pragma unroll
    for (int jj = 0; jj < 2; ++jj) {
      const int j = 2 * q + jj;
      const float* p = xedge + (size_t)e4 * 256 + s * 64 + j * 8;
      v[2 * jj] = ((const float4*)p)[0];
      v[2 * jj + 1] = ((const float4*)p)[1];
    }
#pragma unroll
    for (int jj = 0; jj < 2; ++jj) {
      const int j = 2 * q + jj;
      uint4 u;
      u.x = f2b2(v[2 * jj].x, v[2 * jj].y);
      u.y = f2b2(v[2 * jj].z, v[2 * jj].w);
      u.z = f2b2(v[2 * jj + 1].x, v[2 * jj + 1].y);
      u.w = f2b2(v[2 * jj + 1].z, v[2 * jj + 1].w);
      *(uint4*)(smem + buf * 8192 + r4 * 128 + ((j ^ rb) << 4)) = u;
    }
  };
  // one K-step of 64: A from LDS, B direct-to-VGPR from packed weights
  auto compute1 = [&](int k) {
    const char* A = smem + (k & 1) * 8192;
    const char* wb = (const char*)wt1ep + (size_t)k * 32768;
    __builtin_amdgcn_s_setprio(1);
#pragma unroll
    for (int ks = 0; ks < 2; ++ks) {
      short8 bf[4], af[4];
#pragma unroll
      for (int ni = 0; ni < 4; ++ni) {
        const int n = w * 64 + ni * 16 + lr;
        bf[ni] = *(const short8*)(wb + n * 128 + (((ks * 4 + lk) ^ (n & 7)) << 4));
      }
#pragma unroll
      for (int mi = 0; mi < 4; ++mi) {
        const int m = mi * 16 + lr;
        af[mi] = *(const short8*)(A + m * 128 + (((ks * 4 + lk) ^ (m & 7)) << 4));
      }
#pragma unroll
      for (int mi = 0; mi < 4; ++mi)
#pragma unroll
        for (int ni = 0; ni < 4; ++ni)
          acc[mi][ni] = __builtin_amdgcn_mfma_f32_16x16x32_bf16(
              af[mi], bf[ni], acc[mi][ni], 0, 0, 0);
    }
    __builtin_amdgcn_s_setprio(0);
  };

  // ---- GEMM1: Xe@W1e, 4 K-steps, A dbuf ----
  stageA(0, 0);
  __syncthreads();
  for (int k = 0; k < 4; ++k) {
    if (k + 1 < 4) stageA(k + 1, (k + 1) & 1);
    compute1(k);
    __syncthreads();
  }

  // ---- P-gather add + bias + ReLU -> Hs (32KB, aliases A-dbuf) ----
  char* Hs = smem;
  float bias4[4];
#pragma unroll
  for (int ni = 0; ni < 4; ++ni) bias4[ni] = b1[w * 64 + ni * 16 + lr];
#pragma unroll
  for (int mi = 0; mi < 4; ++mi) {
    uint2 pls[4], pld[4];
#pragma unroll
    for (int r = 0; r < 4; ++r) {
      const int m = mi * 16 + lk * 4 + r;
      const int si = sIdx[m], di = dIdx[m];
      pls[r] = *(const uint2*)((const char*)Ps + (size_t)si * 512 + lr * 32 + w * 8);
      pld[r] = *(const uint2*)((const char*)Pd + (size_t)di * 512 + lr * 32 + w * 8);
    }
#pragma unroll
    for (int ni = 0; ni < 4; ++ni) {
      const int col = w * 64 + ni * 16 + lr;
      const int cole = col & ~1;
      const int chunk = cole >> 3;
      const int cb = (cole & 6) * 2;
      float v[4], p[4];
#pragma unroll
      for (int r = 0; r < 4; ++r) {
        const unsigned us = (ni < 2) ? (pls[r].x >> (16 * ni)) : (pls[r].y >> (16 * (ni - 2)));
        const unsigned ud = (ni < 2) ? (pld[r].x >> (16 * ni)) : (pld[r].y >> (16 * (ni - 2)));
        float x = acc[mi][ni][r] + bias4[ni] + b2f(us) + b2f(ud);
        v[r] = x > 0.f ? x : 0.f;
        acc[mi][ni][r] = 0.f;
      }
#pragma unroll
      for (int r = 0; r < 4; ++r) p[r] = __shfl_xor(v[r], 1, 64);
      const int r0 = (lr & 1) ? 2 : 0;
#pragma unroll
      for (int rr = 0; rr < 2; ++rr) {
        const int r = r0 + rr;
        const int row = mi * 16 + lk * 4 + r;
        const float lo = (lr & 1) ? p[r] : v[r];
        const float hi = (lr & 1) ? v[r] : p[r];
        *(unsigned int*)(Hs + row * 512 + ((chunk ^ (row & 7)) << 4) + cb) =
            f2b2(lo, hi);
      }
    }
  }
  __syncthreads();

  // ---- GEMM2: K=256 over Hs, B direct-to-VGPR ping-pong ----
  short8 bfA[4], bfB[4];
  auto loadB2 = [&](int pair, short8 (&bf)[4]) {
    const char* wb = (const char*)wt2p + (size_t)(pair >> 1) * 32768;
    const int ksl = (pair & 1) * 4 + lk;
#pragma unroll
    for (int ni = 0; ni < 4; ++ni) {
      const int n = w * 64 + ni * 16 + lr;
      bf[ni] = *(const short8*)(wb + n * 128 + ((ksl ^ (n & 7)) << 4));
    }
  };
  auto mfmaH = [&](int pair, short8 (&bf)[4]) {
    const int j = (pair >> 1) * 8 + (pair & 1) * 4 + lk;
    __builtin_amdgcn_s_setprio(1);
#pragma unroll
    for (int mi = 0; mi < 4; ++mi) {
      const int m = mi * 16 + lr;
      short8 af = *(const short8*)(Hs + m * 512 + ((j ^ (m & 7)) << 4));
#pragma unroll
      for (int ni = 0; ni < 4; ++ni)
        acc[mi][ni] = __builtin_amdgcn_mfma_f32_16x16x32_bf16(
            af, bf[ni], acc[mi][ni], 0, 0, 0);
    }
    __builtin_amdgcn_s_setprio(0);
  };
  loadB2(0, bfA);
#pragma unroll
  for (int pair = 0; pair < 8; pair += 2) {
    if (pair + 1 < 8) loadB2(pair + 1, bfB);
    mfmaH(pair, bfA);
    if (pair + 2 < 8) loadB2(pair + 2, bfA);
    if (pair + 1 < 8) mfmaH(pair + 1, bfB);
  }
  __syncthreads();   // Hs reads done before outst overwrites

  // ---- bias + coalesced f32 store via LDS (four 16-row passes) ----
  float* outst = (float*)smem;
#pragma unroll
  for (int p = 0; p < 4; ++p) {
#pragma unroll
    for (int ni = 0; ni < 4; ++ni) {
      const int col = w * 64 + ni * 16 + lr;
      const float bias = b2[col];
#pragma unroll
      for (int r = 0; r < 4; ++r)
        outst[(lk * 4 + r) * LDO + col] = acc[p][ni][r] + bias;
    }
    __syncthreads();
#pragma unroll
    for (int it = 0; it < 4; ++it) {
      const int idx = it * 1024 + t * 4;
      const int lrow = idx >> 8;
      const int cc = idx & 255;
      const int grow = ebase + p * 16 + lrow;
      if (grow < E)
        *(float4*)(out + (size_t)grow * 256 + cc) =
            *(const float4*)(outst + lrow * LDO + cc);
    }
    __syncthreads();
  }
}

// ---- Fallback (small ws): R11 full kernel (verified), BM=256 ----
__global__ __launch_bounds__(512) void edge_mlp_fb(
    const float* __restrict__ xnode, const float* __restrict__ xedge,
    const int* __restrict__ eidx,
    const unsigned short* __restrict__ wt1p, const float* __restrict__ b1,
    const unsigned short* __restrict__ wt2p, const float* __restrict__ b2,
    float* __restrict__ out, int E) {
  __shared__ __align__(16) char smem[131072];

  const int t = threadIdx.x, w = t >> 6, l = t & 63;
  const int lr = l & 15, lk = l >> 4;
  const int wr = w >> 2, wc = w & 3;
  const int ebase = blockIdx.x * 256;

  const int r2 = t >> 1;
  int e2 = ebase + r2;
  if (e2 >= E) e2 = E - 1;
  const int ns2 = eidx[e2], nd2 = eidx[(size_t)E + e2];

  f32x4 acc[8][4];
#pragma unroll
  for (int i = 0; i < 8; ++i)
#pragma unroll
    for (int j = 0; j < 4; ++j) acc[i][j] = (f32x4)0.0f;

  auto stageB = [&](int step, int buf) {
    const char* g = (const char*)wt1p + (size_t)step * 32768 + (t << 4);
    char* d = smem + 65536 + buf * 32768 + (w << 10) + (l << 4);
#pragma unroll
    for (int q = 0; q < 4; ++q) gload16(g + q * 8192, d + q * 8192);
  };
  auto stageA_f32 = [&](const float* base, int rowid, int coloff, int buf) {
    const int rb = r2 & 7;
    float4 v[8];
#pragma unroll
    for (int jj = 0; jj < 4; ++jj) {
      const int j = (t & 1) * 4 + jj;
      const float* p = base + (size_t)rowid * 256 + coloff + j * 8;
      v[2 * jj] = ((const float4*)p)[0];
      v[2 * jj + 1] = ((const float4*)p)[1];
    }
#pragma unroll
    for (int jj = 0; jj < 4; ++jj) {
      const int j = (t & 1) * 4 + jj;
      uint4 u;
      u.x = f2b2(v[2 * jj].x, v[2 * jj].y);
      u.y = f2b2(v[2 * jj].z, v[2 * jj].w);
      u.z = f2b2(v[2 * jj + 1].x, v[2 * jj + 1].y);
      u.w = f2b2(v[2 * jj + 1].z, v[2 * jj + 1].w);
      *(uint4*)(smem + buf * 32768 + r2 * 128 + ((j ^ rb) << 4)) = u;
    }
  };
  auto stageA = [&](int s, int buf) {
    if (s < 4)       stageA_f32(xnode, ns2, s * 64, buf);
    else if (s < 8)  stageA_f32(xnode, nd2, (s - 4) * 64, buf);
    else             stageA_f32(xedge, e2, (s - 8) * 64, buf);
  };
  auto compute = [&](int k) {
    const char* A = smem + (k & 1) * 32768;
    const char* B = smem + 65536 + (k & 1) * 32768;
    __builtin_amdgcn_s_setprio(1);
#pragma unroll
    for (int ks = 0; ks < 2; ++ks) {
      short8 bf[4];
#pragma unroll
      for (int ni = 0; ni < 4; ++ni) {
        const int n = wc * 64 + ni * 16 + lr;
        bf[ni] = *(const short8*)(B + n * 128 + (((ks * 4 + lk) ^ (n & 7)) << 4));
      }
#pragma unroll
      for (int mi = 0; mi < 8; ++mi) {
        const int m = wr * 128 + mi * 16 + lr;
        short8 af = *(const short8*)(A + m * 128 + (((ks * 4 + lk) ^ (m & 7)) << 4));
#pragma unroll
        for (int ni = 0; ni < 4; ++ni)
          acc[mi][ni] = __builtin_amdgcn_mfma_f32_16x16x32_bf16(
              af, bf[ni], acc[mi][ni], 0, 0, 0);
      }
    }
    __builtin_amdgcn_s_setprio(0);
  };

  stageA(0, 0);
  stageB(0, 0);
  __syncthreads();
  for (int k = 0; k < 12; ++k) {
    if (k + 1 < 12) {
      stageB(k + 1, (k + 1) & 1);
      stageA(k + 1, (k + 1) & 1);
    }
    compute(k);
    __syncthreads();
  }

  char* Hs = smem;
#pragma unroll
  for (int ni = 0; ni < 4; ++ni) {
    const int col = wc * 64 + ni * 16 + lr;
    const float bias = b1[col];
    const int cole = col & ~1;
    const int chunk = cole >> 3;
    const int cb = (cole & 6) * 2;
#pragma unroll
    for (int mi = 0; mi < 8; ++mi) {
      float v[4], p[4];
#pragma unroll
      for (int r = 0; r < 4; ++r) {
        float x = acc[mi][ni][r] + bias;
        v[r] = x > 0.f ? x : 0.f;
        acc[mi][ni][r] = 0.f;
      }
#pragma unroll
      for (int r = 0; r < 4; ++r) p[r] = __shfl_xor(v[r], 1, 64);
      const int r0 = (lr & 1) ? 2 : 0;
#pragma unroll
      for (int rr = 0; rr < 2; ++rr) {
        const int r = r0 + rr;
        const int row = wr * 128 + mi * 16 + lk * 4 + r;
        const float lo = (lr & 1) ? p[r] : v[r];
        const float hi = (lr & 1) ? v[r] : p[r];
        *(unsigned int*)(Hs + row * 512 + ((chunk ^ (row & 7)) << 4) + cb) =
            f2b2(lo, hi);
      }
    }
  }
  __syncthreads();

  short8 bfA[4], bfB[4];
  auto loadB2 = [&](int pair, short8 (&bf)[4]) {
    const char* wb = (const char*)wt2p + (pair >> 1) * 32768;
    const int ksl = (pair & 1) * 4 + lk;
#pragma unroll
    for (int ni = 0; ni < 4; ++ni) {
      const int n = wc * 64 + ni * 16 + lr;
      bf[ni] = *(const short8*)(wb + n * 128 + ((ksl ^ (n & 7)) << 4));
    }
  };
  auto mfmaH = [&](int pair, short8 (&bf)[4]) {
    const int j = (pair >> 1) * 8 + (pair & 1) * 4 + lk;
    __builtin_amdgcn_s_setprio(1);
#pragma unroll
    for (int mi = 0; mi < 8; ++mi) {
      const int m = wr * 128 + mi * 16 + lr;
      short8 af = *(const short8*)(Hs + m * 512 + ((j ^ (m & 7)) << 4));
#pragma unroll
      for (int ni = 0; ni < 4; ++ni)
        acc[mi][ni] = __builtin_amdgcn_mfma_f32_16x16x32_bf16(
            af, bf[ni], acc[mi][ni], 0, 0, 0);
    }
    __builtin_amdgcn_s_setprio(0);
  };
  loadB2(0, bfA);
#pragma unroll
  for (int pair = 0; pair < 8; pair += 2) {
    if (pair + 1 < 8) loadB2(pair + 1, bfB);
    mfmaH(pair, bfA);
    if (pair + 2 < 8) loadB2(pair + 2, bfA);
    if (pair + 1 < 8) mfmaH(pair + 1, bfB);
  }

  float* outst = (float*)smem;
#pragma unroll
  for (int p = 0; p < 4; ++p) {
    __syncthreads();
    if (wr == (p >> 1)) {
#pragma unroll
      for (int ni = 0; ni < 4; ++ni) {
        const int col = wc * 64 + ni * 16 + lr;
        const float bias = b2[col];
#pragma unroll
        for (int mh = 0; mh < 4; ++mh) {
          const int mi = (p & 1) * 4 + mh;
#pragma unroll
          for (int r = 0; r < 4; ++r)
            outst[(mh * 16 + lk * 4 + r) * LDO + col] = acc[mi][ni][r] + bias;
        }
      }
    }
    __syncthreads();
#pragma unroll
    for (int it = 0; it < 8; ++it) {
      const int idx = it * 2048 + t * 4;
      const int lrow = idx >> 8;
      const int cc = idx & 255;
      const int grow = ebase + p * 64 + lrow;
      if (grow < E)
        *(float4*)(out + (size_t)grow * 256 + cc) =
            *(const float4*)(outst + lrow * LDO + cc);
    }
  }
}

extern "C" void kernel_launch(void* const* d_in, const int* in_sizes, int n_in,
                              void* d_out, int out_size, void* d_ws, size_t ws_size,
                              hipStream_t stream) {
  const float* xnode = (const float*)d_in[0];
  const float* xedge = (const float*)d_in[1];
  const int* eidx = (const int*)d_in[2];
  const float* W1 = (const float*)d_in[3];
  const float* b1 = (const float*)d_in[4];
  const float* W2 = (const float*)d_in[5];
  const float* b2 = (const float*)d_in[6];
  float* out = (float*)d_out;

  const int NN = in_sizes[0] / 256;   // 50000
  const int E = in_sizes[1] / 256;    // 300000

  char* ws = (char*)d_ws;
  const size_t need_new = 4 * 131072 + (size_t)2 * NN * 512;

  if (ws_size >= need_new) {
    unsigned short* wt1sp = (unsigned short*)ws;                    // 128KB
    unsigned short* wt1dp = (unsigned short*)(ws + 131072);         // 128KB
    unsigned short* wt1ep = (unsigned short*)(ws + 262144);         // 128KB
    unsigned short* wt2p  = (unsigned short*)(ws + 393216);         // 128KB
    unsigned short* Ps    = (unsigned short*)(ws + 524288);         // NN*512B x2
    unsigned short* Pd    = Ps + (size_t)NN * 256;

    prep_w_kernel<<<256, 256, 0, stream>>>(W1, wt1sp, 65536);
    prep_w_kernel<<<256, 256, 0, stream>>>(W1 + 65536, wt1dp, 65536);
    prep_w_kernel<<<256, 256, 0, stream>>>(W1 + 131072, wt1ep, 65536);
    prep_w_kernel<<<256, 256, 0, stream>>>(W2, wt2p, 65536);

    node_p_kernel<<<dim3((NN + 255) / 256, 2), 512, 0, stream>>>(xnode, wt1sp,
                                                                 Ps, NN);
    edge_mlp_lite<<<(E + 63) / 64, 256, 0, stream>>>(xedge, eidx, Ps, Pd,
                                                     wt1ep, b1, wt2p, b2,
                                                     out, E);
  } else {
    unsigned short* wt1p = (unsigned short*)ws;                     // 12x32KB
    unsigned short* wt2p = (unsigned short*)(ws + 12 * 32768);      //  4x32KB
    prep_w_kernel<<<(12 * 16384 + 255) / 256, 256, 0, stream>>>(W1, wt1p,
                                                                12 * 16384);
    prep_w_kernel<<<256, 256, 0, stream>>>(W2, wt2p, 65536);
    edge_mlp_fb<<<(E + 255) / 256, 512, 0, stream>>>(xnode, xedge, eidx,
                                                     wt1p, b1, wt2p, b2,
                                                     out, E);
  }
}